// Round 7
// baseline (20.910 us; speedup 1.0000x reference)
//
#include <hip/hip_runtime.h>

// Problem constants (fixed by the reference)
#define NB   200    // dialogues
#define LL   50     // utterances per dialogue
#define ND   128    // feature dim

typedef __attribute__((ext_vector_type(8))) short bf16x8;  // 8 bf16 (4 VGPRs)
typedef __attribute__((ext_vector_type(4))) float f32x4;

// Block = one dialogue, 512 threads (8 waves). LDS: only the padded feats tile.
//   featsB : bf16 [192][FS]  (node = 64*m + t; rows t>=50 zeroed)
// FS=136 shorts (272B): fragment b128 reads land uniformly on the 8 bank-slots.
#define FS   136
#define SMEM_BYTES (192 * FS * 2)   // 52,224 B

__device__ __forceinline__ short f2bf(float x) {          // f32 -> bf16 RTNE
    unsigned u = __float_as_uint(x);
    return (short)((u + 0x7fffu + ((u >> 16) & 1u)) >> 16);
}

__device__ __forceinline__ float bf2f(short h) {          // bf16 -> f32 (exact)
    return __uint_as_float(((unsigned)(unsigned short)h) << 16);
}

__device__ __forceinline__ bf16x8 pack8(f32x4 lo, f32x4 hi) {
    bf16x8 r;
    r[0] = f2bf(lo[0]); r[1] = f2bf(lo[1]); r[2] = f2bf(lo[2]); r[3] = f2bf(lo[3]);
    r[4] = f2bf(hi[0]); r[5] = f2bf(hi[1]); r[6] = f2bf(hi[2]); r[7] = f2bf(hi[3]);
    return r;
}

__launch_bounds__(512, 2)
__global__ void hgcn_fused(const float* __restrict__ a,
                           const float* __restrict__ v,
                           const float* __restrict__ l,
                           const float* __restrict__ qmask,
                           const float* __restrict__ W1,
                           const float* __restrict__ b1,
                           const float* __restrict__ se,
                           const float* __restrict__ kap,
                           float* __restrict__ out) {
    extern __shared__ char smem[];
    short* featsB = (short*)smem;                 // [192][FS]

    const int b    = blockIdx.x;
    const int tid  = threadIdx.x;
    const int lane = tid & 63;
    const int w    = tid >> 6;    // wave = dim-tile dt (0..7)
    const int r    = lane & 15;   // fragment row
    const int q    = lane >> 4;   // fragment k-chunk / node sub-group
    const int d    = 16 * w + r;  // this lane's output dim

    const f32x4* a4  = (const f32x4*)a;
    const f32x4* v4  = (const f32x4*)v;
    const f32x4* l4  = (const f32x4*)l;
    const f32x4* se4 = (const f32x4*)se;
    const f32x4* W14 = (const f32x4*)W1;
    f32x4* out4 = (f32x4*)out;

    // ---- Early independent loads (overlap with staging) --------------------
    const f32x4 kap4 = *(const f32x4*)kap;
    const float bias = b1[d];
    bf16x8 wfr[4];                                // W1 frags straight from global
    #pragma unroll
    for (int ks = 0; ks < 4; ++ks) {
        f32x4 g0 = W14[(16 * w + r) * 32 + ks * 8 + q * 2];
        f32x4 g1 = W14[(16 * w + r) * 32 + ks * 8 + q * 2 + 1];
        wfr[ks] = pack8(g0, g1);
    }

    // ---- Phase 1: stage feats bf16, padded node space [192] ----------------
    for (int i = tid; i < 3072; i += 512) {
        int prow = i >> 4, c8 = i & 15;           // c8 = 8-float chunk
        int m = prow >> 6, t = prow & 63;
        f32x4 f0 = {0.f, 0.f, 0.f, 0.f}, f1 = {0.f, 0.f, 0.f, 0.f};
        if (t < LL) {
            const f32x4* src = (m == 0) ? l4 : ((m == 1) ? a4 : v4);
            int base = (b * LL + t) * 32 + c8 * 2;
            f0 = src[base]; f1 = src[base + 1];
            if (m == 0) {
                int qb  = (t * NB + b) * 2;
                int spk = qmask[qb + 1] > qmask[qb] ? 1 : 0;
                f0 += se4[spk * 32 + c8 * 2];
                f1 += se4[spk * 32 + c8 * 2 + 1];
            }
        }
        *(bf16x8*)&featsB[prow * FS + c8 * 8] = pack8(f0, f1);
    }
    __syncthreads();

    // ---- Phase 2: MFMA GEMM, D-layout = (dim in lane, nodes in regs) -------
    // mfma(featsfrag, W1frag): lane holds x[node = 16*nt + 4*q + e][dim = d],
    // e = acc element. 12 node tiles cover padded 192 rows.
    f32x4 acc[12];
    #pragma unroll
    for (int nt = 0; nt < 12; ++nt) acc[nt] = (f32x4){0.f, 0.f, 0.f, 0.f};
    #pragma unroll
    for (int ks = 0; ks < 4; ++ks)
        #pragma unroll
        for (int nt = 0; nt < 12; ++nt) {
            bf16x8 af = *(const bf16x8*)&featsB[(16 * nt + r) * FS + ks * 32 + q * 8];
            acc[nt] = __builtin_amdgcn_mfma_f32_16x16x32_bf16(af, wfr[ks], acc[nt], 0, 0, 0);
        }

    // ---- Phase 3: feats-half of output from LDS (stores drain under P4) ----
    for (int i = tid; i < 3072; i += 512) {
        int prow = i >> 4, c8 = i & 15;
        int m = prow >> 6, t = prow & 63;
        if (t < LL) {
            bf16x8 hv = *(const bf16x8*)&featsB[prow * FS + c8 * 8];
            f32x4 f0, f1;
            f0[0] = bf2f(hv[0]); f0[1] = bf2f(hv[1]); f0[2] = bf2f(hv[2]); f0[3] = bf2f(hv[3]);
            f1[0] = bf2f(hv[4]); f1[1] = bf2f(hv[5]); f1[2] = bf2f(hv[6]); f1[3] = bf2f(hv[7]);
            size_t o = (size_t)(b * LL + t) * 192 + m * 64 + c8 * 2;
            out4[o]     = f0;
            out4[o + 1] = f1;
        }
    }

    // ---- Phase 4: bias + validity mask (t>=50 slots stay exactly 0) --------
    #pragma unroll
    for (int nt = 0; nt < 12; ++nt) {
        int t0 = 16 * (nt & 3) + 4 * q;
        #pragma unroll
        for (int e = 0; e < 4; ++e)
            acc[nt][e] = (t0 + e < LL) ? acc[nt][e] + bias : 0.0f;
    }

    // ---- Phase 5: 4 HGCN iterations, fully wave-local (0 barriers) ---------
    // S_m = sum over t (15 local adds + 2 shfl); c_t register-local across m.
    const float inv = 1.0f / 51.0f;
    #pragma unroll
    for (int it = 0; it < 4; ++it) {
        const float f = kap4[it] * inv;
        const float g = 1.0f - 2.0f * f;          // x' = relu(g*x + f*(S+c))
        float S[3];
        #pragma unroll
        for (int m = 0; m < 3; ++m) {
            f32x4 s4 = acc[4 * m] + acc[4 * m + 1] + acc[4 * m + 2] + acc[4 * m + 3];
            float s = s4[0] + s4[1] + s4[2] + s4[3];
            s += __shfl_xor(s, 16, 64);
            s += __shfl_xor(s, 32, 64);
            S[m] = s;
        }
        #pragma unroll
        for (int j = 0; j < 4; ++j) {
            int t0 = 16 * j + 4 * q;
            #pragma unroll
            for (int e = 0; e < 4; ++e) {
                float c = acc[j][e] + acc[4 + j][e] + acc[8 + j][e];
                bool valid = (t0 + e) < LL;
                #pragma unroll
                for (int m = 0; m < 3; ++m) {
                    float xv = acc[4 * m + j][e];
                    float nv = fmaxf(fmaf(f, S[m] + c, g * xv), 0.0f);
                    acc[4 * m + j][e] = valid ? nv : 0.0f;
                }
            }
        }
    }

    // ---- Phase 6: x-half of output straight from registers ----------------
    const size_t ob = (size_t)b * LL * 768 + 128 + d;
    #pragma unroll
    for (int m = 0; m < 3; ++m)
        #pragma unroll
        for (int j = 0; j < 4; ++j) {
            int t0 = 16 * j + 4 * q;
            #pragma unroll
            for (int e = 0; e < 4; ++e) {
                int t = t0 + e;
                if (t < LL)
                    out[ob + (size_t)t * 768 + m * 256] = acc[4 * m + j][e];
            }
        }
}

extern "C" void kernel_launch(void* const* d_in, const int* in_sizes, int n_in,
                              void* d_out, int out_size, void* d_ws, size_t ws_size,
                              hipStream_t stream) {
    const float* a     = (const float*)d_in[0];
    const float* v     = (const float*)d_in[1];
    const float* l     = (const float*)d_in[2];
    const float* qmask = (const float*)d_in[3];
    const float* W1    = (const float*)d_in[4];
    const float* b1    = (const float*)d_in[5];
    const float* se    = (const float*)d_in[6];
    const float* kap   = (const float*)d_in[7];
    // d_in[8] = edge_index (closed-form structure; unused), d_in[9] = epoch (unused)
    float* out = (float*)d_out;

    hipFuncSetAttribute((const void*)hgcn_fused,
                        hipFuncAttributeMaxDynamicSharedMemorySize, SMEM_BYTES);
    hgcn_fused<<<NB, 512, SMEM_BYTES, stream>>>(a, v, l, qmask, W1, b1, se, kap, out);
}

// Round 8
// 17.933 us; speedup vs baseline: 1.1660x; 1.1660x over previous
//
#include <hip/hip_runtime.h>

// Problem constants (fixed by the reference)
#define NB   200    // dialogues
#define LL   50     // utterances per dialogue
#define ND   128    // feature dim

typedef __attribute__((ext_vector_type(8))) short bf16x8;  // 8 bf16 (4 VGPRs)
typedef __attribute__((ext_vector_type(4))) float f32x4;

// Block = one dialogue, 1024 threads (16 waves). LDS: only the padded feats tile.
//   featsB : bf16 [192][FS]  (padded node = 64*m + t; rows t>=50 zeroed)
#define FS   136
#define SMEM_BYTES (192 * FS * 2)   // 52,224 B

__device__ __forceinline__ short f2bf(float x) {          // f32 -> bf16 RTNE
    unsigned u = __float_as_uint(x);
    return (short)((u + 0x7fffu + ((u >> 16) & 1u)) >> 16);
}

__device__ __forceinline__ bf16x8 pack8(f32x4 lo, f32x4 hi) {
    bf16x8 r;
    r[0] = f2bf(lo[0]); r[1] = f2bf(lo[1]); r[2] = f2bf(lo[2]); r[3] = f2bf(lo[3]);
    r[4] = f2bf(hi[0]); r[5] = f2bf(hi[1]); r[6] = f2bf(hi[2]); r[7] = f2bf(hi[3]);
    return r;
}

__launch_bounds__(1024, 4)
__global__ void hgcn_fused(const float* __restrict__ a,
                           const float* __restrict__ v,
                           const float* __restrict__ l,
                           const float* __restrict__ qmask,
                           const float* __restrict__ W1,
                           const float* __restrict__ b1,
                           const float* __restrict__ se,
                           const float* __restrict__ kap,
                           float* __restrict__ out) {
    extern __shared__ char smem[];
    short* featsB = (short*)smem;                 // [192][FS]

    const int b    = blockIdx.x;
    const int tid  = threadIdx.x;
    const int lane = tid & 63;
    const int w    = tid >> 6;    // wave 0..15
    const int r    = lane & 15;
    const int q    = lane >> 4;

    const f32x4* a4  = (const f32x4*)a;
    const f32x4* v4  = (const f32x4*)v;
    const f32x4* l4  = (const f32x4*)l;
    const f32x4* se4 = (const f32x4*)se;
    const f32x4* W14 = (const f32x4*)W1;
    f32x4* out4 = (f32x4*)out;

    // ---- Early independent loads for the GEMM waves (overlap with staging) --
    f32x4 kap4 = {0.f, 0.f, 0.f, 0.f};
    float bias = 0.0f;
    bf16x8 wfr[4];
    const int d = 16 * w + r;                     // output dim (waves 0..7 only)
    if (tid < 512) {
        kap4 = *(const f32x4*)kap;
        bias = b1[d];
        #pragma unroll
        for (int ks = 0; ks < 4; ++ks) {
            f32x4 g0 = W14[d * 32 + ks * 8 + q * 2];
            f32x4 g1 = W14[d * 32 + ks * 8 + q * 2 + 1];
            wfr[ks] = pack8(g0, g1);
        }
    }

    // ---- Phase 1: stage feats bf16, padded node space [192] (all threads) --
    for (int i = tid; i < 3072; i += 1024) {
        int prow = i >> 4, c8 = i & 15;           // c8 = 8-float chunk
        int m = prow >> 6, t = prow & 63;
        f32x4 f0 = {0.f, 0.f, 0.f, 0.f}, f1 = {0.f, 0.f, 0.f, 0.f};
        if (t < LL) {
            const f32x4* src = (m == 0) ? l4 : ((m == 1) ? a4 : v4);
            int base = (b * LL + t) * 32 + c8 * 2;
            f0 = src[base]; f1 = src[base + 1];
            if (m == 0) {
                int qb  = (t * NB + b) * 2;
                int spk = qmask[qb + 1] > qmask[qb] ? 1 : 0;
                f0 += se4[spk * 32 + c8 * 2];
                f1 += se4[spk * 32 + c8 * 2 + 1];
            }
        }
        *(bf16x8*)&featsB[prow * FS + c8 * 8] = pack8(f0, f1);
    }
    __syncthreads();                              // the only barrier

    if (tid < 512) {
        // ---- Waves 0-7: MFMA GEMM, acc IS the iteration state --------------
        // mfma(featsfrag, W1frag): lane holds x[node = 16*nt + 4*q + e][dim=d]
        f32x4 acc[12];
        #pragma unroll
        for (int nt = 0; nt < 12; ++nt) acc[nt] = (f32x4){0.f, 0.f, 0.f, 0.f};
        #pragma unroll
        for (int ks = 0; ks < 4; ++ks)
            #pragma unroll
            for (int nt = 0; nt < 12; ++nt) {
                bf16x8 af = *(const bf16x8*)&featsB[(16 * nt + r) * FS + ks * 32 + q * 8];
                acc[nt] = __builtin_amdgcn_mfma_f32_16x16x32_bf16(af, wfr[ks], acc[nt], 0, 0, 0);
            }

        // bias + validity mask (padded t>=50 slots stay exactly 0)
        #pragma unroll
        for (int nt = 0; nt < 12; ++nt) {
            int t0 = 16 * (nt & 3) + 4 * q;
            #pragma unroll
            for (int e = 0; e < 4; ++e)
                acc[nt][e] = (t0 + e < LL) ? acc[nt][e] + bias : 0.0f;
        }

        // ---- 4 HGCN iterations, fully wave-local (0 barriers) --------------
        const float inv = 1.0f / 51.0f;
        #pragma unroll
        for (int it = 0; it < 4; ++it) {
            const float f = kap4[it] * inv;
            const float g = 1.0f - 2.0f * f;      // x' = relu(g*x + f*(S+c))
            float S[3];
            #pragma unroll
            for (int m = 0; m < 3; ++m) {
                f32x4 s4 = acc[4 * m] + acc[4 * m + 1] + acc[4 * m + 2] + acc[4 * m + 3];
                float s = s4[0] + s4[1] + s4[2] + s4[3];
                s += __shfl_xor(s, 16, 64);       // reduce over the 4 q-groups
                s += __shfl_xor(s, 32, 64);
                S[m] = s;
            }
            #pragma unroll
            for (int j = 0; j < 4; ++j) {
                int t0 = 16 * j + 4 * q;
                #pragma unroll
                for (int e = 0; e < 4; ++e) {
                    float c = acc[j][e] + acc[4 + j][e] + acc[8 + j][e];
                    bool valid = (t0 + e) < LL;
                    #pragma unroll
                    for (int m = 0; m < 3; ++m) {
                        float xv = acc[4 * m + j][e];
                        float nv = fmaxf(fmaf(f, S[m] + c, g * xv), 0.0f);
                        acc[4 * m + j][e] = valid ? nv : 0.0f;
                    }
                }
            }
        }

        // ---- x-half of output straight from registers ----------------------
        const size_t ob = (size_t)b * LL * 768 + 128 + d;
        #pragma unroll
        for (int m = 0; m < 3; ++m)
            #pragma unroll
            for (int j = 0; j < 4; ++j) {
                int t0 = 16 * j + 4 * q;
                #pragma unroll
                for (int e = 0; e < 4; ++e) {
                    int t = t0 + e;
                    if (t < LL)
                        out[ob + (size_t)t * 768 + m * 256] = acc[4 * m + j][e];
                }
            }
    } else {
        // ---- Waves 8-15 (concurrent with GEMM): feats-half of output -------
        // Sourced from global (L2-hot second read) -> exact f32; keeps the
        // LDS pipe free for the GEMM fragment reads.
        for (int i = tid - 512; i < 2400; i += 512) {
            int row = i >> 4, c8 = i & 15;
            int m = row >= 100 ? 2 : (row >= 50 ? 1 : 0);
            int t = row - m * 50;
            const f32x4* src = (m == 0) ? l4 : ((m == 1) ? a4 : v4);
            int base = (b * LL + t) * 32 + c8 * 2;
            f32x4 f0 = src[base], f1 = src[base + 1];
            if (m == 0) {
                int qb  = (t * NB + b) * 2;
                int spk = qmask[qb + 1] > qmask[qb] ? 1 : 0;
                f0 += se4[spk * 32 + c8 * 2];
                f1 += se4[spk * 32 + c8 * 2 + 1];
            }
            size_t o = (size_t)(b * LL + t) * 192 + m * 64 + c8 * 2;
            out4[o]     = f0;
            out4[o + 1] = f1;
        }
    }
}

extern "C" void kernel_launch(void* const* d_in, const int* in_sizes, int n_in,
                              void* d_out, int out_size, void* d_ws, size_t ws_size,
                              hipStream_t stream) {
    const float* a     = (const float*)d_in[0];
    const float* v     = (const float*)d_in[1];
    const float* l     = (const float*)d_in[2];
    const float* qmask = (const float*)d_in[3];
    const float* W1    = (const float*)d_in[4];
    const float* b1    = (const float*)d_in[5];
    const float* se    = (const float*)d_in[6];
    const float* kap   = (const float*)d_in[7];
    // d_in[8] = edge_index (closed-form structure; unused), d_in[9] = epoch (unused)
    float* out = (float*)d_out;

    hipFuncSetAttribute((const void*)hgcn_fused,
                        hipFuncAttributeMaxDynamicSharedMemorySize, SMEM_BYTES);
    hgcn_fused<<<NB, 1024, SMEM_BYTES, stream>>>(a, v, l, qmask, W1, b1, se, kap, out);
}